// Round 22
// baseline (242.208 us; speedup 1.0000x reference)
//
#include <hip/hip_runtime.h>

#define BB 8
#define NN 2048
#define CC 128
#define KMAX 32
#define NEG 0.2f
#define CH 8
#define CHSZ (NN / CH)   // 256
#define CPAD 260         // chunk stride in LDS: (260*c+jj)%32 = (4c+jj)%32 -> 8 distinct banks
#define CAP 32           // per-thread candidate buffer (drain-on-full keeps j order)

using bf16x8 = __attribute__((ext_vector_type(8))) short;  // 8 bf16 (4 VGPRs)
using f32x4  = __attribute__((ext_vector_type(4))) float;  // 4 fp32

// Map f32 to a u32 whose unsigned order == float order (handles negatives).
__device__ __forceinline__ unsigned int f2key(float f) {
  unsigned int b = __float_as_uint(f);
  return (b & 0x80000000u) ? ~b : (b | 0x80000000u);
}

// np-exact f32 squared norm: fl(fl(x^2+y^2)+z^2), no FMA contraction.
__device__ __forceinline__ float sq3(float x, float y, float z) {
  return __fadd_rn(__fadd_rn(__fmul_rn(x, x), __fmul_rn(y, y)), __fmul_rn(z, z));
}

// np-exact f32 distance key: d2 = fl( fl(sq_i+sq_j) - fl(2*dot) ).
__device__ __forceinline__ float d2np(float px, float py, float pz, float sqq,
                                      float qx, float qy, float qz, float sqj) {
  float dot = __fmaf_rn(pz, qz, __fmaf_rn(py, qy, __fmul_rn(px, qx)));
  return __fsub_rn(__fadd_rn(sqq, sqj), __fmul_rn(2.0f, dot));
}

// f32 -> bf16 (round to nearest even), finite inputs.
__device__ __forceinline__ unsigned short f2bf(float f) {
  unsigned int u = __float_as_uint(f);
  return (unsigned short)((u + 0x7fffu + ((u >> 16) & 1u)) >> 16);
}
// bf16 -> f32, exact.
__device__ __forceinline__ float bf2f(unsigned short u) {
  return __uint_as_float(((unsigned int)u) << 16);
}

// 8 consecutive f32 -> bf16x8 A-fragment (bit-identical to the old cvt_x+load).
__device__ __forceinline__ bf16x8 cvt8(const float* __restrict__ p) {
  float4 a = *(const float4*)(p);
  float4 b = *(const float4*)(p + 4);
  bf16x8 r;
  r[0] = (short)f2bf(a.x); r[1] = (short)f2bf(a.y);
  r[2] = (short)f2bf(a.z); r[3] = (short)f2bf(a.w);
  r[4] = (short)f2bf(b.x); r[5] = (short)f2bf(b.y);
  r[6] = (short)f2bf(b.z); r[7] = (short)f2bf(b.w);
  return r;
}

// ---------------------------------------------------------------------------
// 6-proj MFMA body (on-the-fly x conversion), bf16 out.
// ---------------------------------------------------------------------------
__device__ __forceinline__ void proj_body(int z, int mx, int tid,
                                          const float* __restrict__ x,
                                          const unsigned short* __restrict__ wf,
                                          unsigned short* __restrict__ projb) {
  unsigned short* out = projb + (size_t)z * ((size_t)BB * NN * CC);
  int wave = tid >> 6;
  int lane = tid & 63;
  int m0 = (mx * 4 + wave) * 16;
  int quad = lane >> 4;
  int am = m0 + (lane & 15);

  f32x4 acc[8];
#pragma unroll
  for (int nt = 0; nt < 8; ++nt) acc[nt] = (f32x4){0.f, 0.f, 0.f, 0.f};

  const unsigned short* wz = wf + (size_t)z * (8 * 4 * 64 * 8);
#pragma unroll
  for (int ks = 0; ks < 4; ++ks) {
    bf16x8 a = cvt8(x + (size_t)am * CC + ks * 32 + quad * 8);
#pragma unroll
    for (int nt = 0; nt < 8; ++nt) {
      bf16x8 bfr = *(const bf16x8*)(wz + (size_t)(((nt * 4 + ks) * 64 + lane) * 8));
      acc[nt] = __builtin_amdgcn_mfma_f32_16x16x32_bf16(a, bfr, acc[nt], 0, 0, 0);
    }
  }

  int col0 = lane & 15;
#pragma unroll
  for (int nt = 0; nt < 8; ++nt)
#pragma unroll
    for (int r = 0; r < 4; ++r)
      out[(size_t)(m0 + quad * 4 + r) * CC + nt * 16 + col0] = f2bf(acc[nt][r]);
}

// ---------------------------------------------------------------------------
// Wg epilogue MFMA body (on-the-fly x conversion), f32 h out.
// ---------------------------------------------------------------------------
__device__ __forceinline__ void wg_body(int mx, int tid,
                                        const float* __restrict__ x,
                                        const float* __restrict__ pos,
                                        const unsigned short* __restrict__ wf,
                                        const float* __restrict__ wgtail,
                                        const float* __restrict__ bg,
                                        float* __restrict__ h) {
  int wave = tid >> 6;
  int lane = tid & 63;
  int m0 = (mx * 4 + wave) * 16;
  int quad = lane >> 4;
  int am = m0 + (lane & 15);

  f32x4 acc[8];
#pragma unroll
  for (int nt = 0; nt < 8; ++nt) acc[nt] = (f32x4){0.f, 0.f, 0.f, 0.f};

  const unsigned short* wz = wf + (size_t)6 * (8 * 4 * 64 * 8);
#pragma unroll
  for (int ks = 0; ks < 4; ++ks) {
    bf16x8 a = cvt8(x + (size_t)am * CC + ks * 32 + quad * 8);
#pragma unroll
    for (int nt = 0; nt < 8; ++nt) {
      bf16x8 b = *(const bf16x8*)(wz + (size_t)(((nt * 4 + ks) * 64 + lane) * 8));
      acc[nt] = __builtin_amdgcn_mfma_f32_16x16x32_bf16(a, b, acc[nt], 0, 0, 0);
    }
  }

  float posr[4][3];
#pragma unroll
  for (int r = 0; r < 4; ++r) {
    int m = m0 + quad * 4 + r;
    posr[r][0] = pos[m * 3 + 0];
    posr[r][1] = pos[m * 3 + 1];
    posr[r][2] = pos[m * 3 + 2];
  }

  int col0 = lane & 15;
#pragma unroll
  for (int nt = 0; nt < 8; ++nt) {
    int col = nt * 16 + col0;
    float bv = bg[col];
    float t0 = wgtail[col];
    float t1 = wgtail[CC + col];
    float t2 = wgtail[2 * CC + col];
#pragma unroll
    for (int r = 0; r < 4; ++r) {
      float v = acc[nt][r] + bv
              + posr[r][0] * t0 + posr[r][1] * t1 + posr[r][2] * t2;
      v = v > 0.f ? v : NEG * v;
      h[(size_t)(m0 + quad * 4 + r) * CC + col] = v;
    }
  }
}

// ---------------------------------------------------------------------------
// FUSED FRONT (R20 verbatim): blocks [0,512) = knn_p1 (FROZEN R9 body);
// [512,2048) = 6-proj bf16 MFMA; [2048,2304) = Wg epilogue MFMA.
// ---------------------------------------------------------------------------
__global__ __launch_bounds__(256) void fused_front(
    const float* __restrict__ pos,
    unsigned short* __restrict__ cand,
    unsigned int* __restrict__ candk,
    const float* __restrict__ x,
    const unsigned short* __restrict__ wf,
    unsigned short* __restrict__ projb,
    const float* __restrict__ wgtail,
    const float* __restrict__ bg,
    float* __restrict__ h) {
  __shared__ float spx[CH * CPAD], spy[CH * CPAD], spz[CH * CPAD], ssq[CH * CPAD];
  __shared__ unsigned int sred[256];
  __shared__ unsigned short sbuf[256 * CAP];

  if (blockIdx.x < 512) {
    // ---------------- knn_p1: FROZEN R9 body. Do not touch. ----------------
    int b = blockIdx.x >> 6;                       // 64 blocks per batch
    int qbase = (blockIdx.x & 63) * 32;
    const float* pb = pos + (size_t)b * NN * 3;
    for (int t = threadIdx.x; t < NN; t += 256) {
      int a = ((t >> 8) * CPAD) + (t & 255);       // padded SoA address of point t
      float xx = pb[t * 3 + 0];
      float yy = pb[t * 3 + 1];
      float zz = pb[t * 3 + 2];
      spx[a] = xx; spy[a] = yy; spz[a] = zz;
      ssq[a] = sq3(xx, yy, zz);
    }
    __syncthreads();

    int q = qbase + (threadIdx.x >> 3);
    int c = threadIdx.x & 7;
    int qa = ((q >> 8) * CPAD) + (q & 255);
    float px = spx[qa], py = spy[qa], pz = spz[qa];
    float sqq = ssq[qa];

    int abase = c * CPAD;
    int j0 = c * CHSZ;

    unsigned int a0 = 0xFFFFFFFFu, a1 = 0xFFFFFFFFu, a2 = 0xFFFFFFFFu, a3 = 0xFFFFFFFFu;
    for (int jj = 0; jj < CHSZ; ++jj) {
      int a = abase + jj;
      int j = j0 + jj;
      float d2 = d2np(px, py, pz, sqq, spx[a], spy[a], spz[a], ssq[a]);
      unsigned int key = f2key(d2);
      if (j == q) key = 0xFFFFFFFFu;
      if (key < a3) {
        bool c3 = key < a2;
        a3 = c3 ? a2 : key;
        bool c2 = key < a1;
        a2 = c3 ? (c2 ? a1 : key) : a2;
        bool c1 = key < a0;
        a1 = c2 ? (c1 ? a0 : key) : a1;
        a0 = c1 ? key : a0;
      }
    }
    sred[threadIdx.x] = a3;
    __syncthreads();
    if (c == 0) {
      unsigned int m = sred[threadIdx.x];
#pragma unroll
      for (int u = 1; u < 8; ++u) {
        unsigned int v = sred[threadIdx.x + u];
        m = v > m ? v : m;
      }
      sred[threadIdx.x] = m;
    }
    __syncthreads();
    unsigned int T = sred[threadIdx.x & ~7];

    unsigned int ak[KMAX];
    int ai[KMAX];
#pragma unroll
    for (int k = 0; k < KMAX; ++k) { ak[k] = 0xFFFFFFFFu; ai[k] = 0xFFFF; }

    int sbase = threadIdx.x * CAP;
    auto drain = [&](int cnt2) {
      for (int u = 0; u < cnt2; ++u) {
        int jj2 = (int)sbuf[sbase + u];
        int a = abase + jj2;
        int j = j0 + jj2;
        float d2 = d2np(px, py, pz, sqq, spx[a], spy[a], spz[a], ssq[a]);
        unsigned int key = f2key(d2);               // self never buffered
        if (key < ak[KMAX - 1]) {                   // strict: stable ties -> lower j
#pragma unroll
          for (int k = KMAX - 1; k >= 1; --k) {
            bool ck  = key < ak[k];
            bool ckm = key < ak[k - 1];
            unsigned int tk = ckm ? ak[k - 1] : key;
            int          ti = ckm ? ai[k - 1] : j;
            ak[k] = ck ? tk : ak[k];
            ai[k] = ck ? ti : ai[k];
          }
          bool c0b = key < ak[0];
          ak[0] = c0b ? key : ak[0];
          ai[0] = c0b ? j : ai[0];
        }
      }
    };

    int cnt = 0;
    for (int jj = 0; jj < CHSZ; ++jj) {
      int a = abase + jj;
      int j = j0 + jj;
      float d2 = d2np(px, py, pz, sqq, spx[a], spy[a], spz[a], ssq[a]);
      unsigned int key = f2key(d2);
      if (j == q) key = 0xFFFFFFFFu;               // self fails gate (T < max)
      if (key <= T) {
        if (cnt == CAP) { drain(CAP); cnt = 0; }   // rare; preserves j order
        sbuf[sbase + cnt] = (unsigned short)jj;
        ++cnt;
      }
    }
    drain(cnt);

    size_t obase = (((size_t)(b * NN + q)) * CH + c) * KMAX;
    unsigned short* oc = cand + obase;
    unsigned int* ok = candk + obase;
#pragma unroll
    for (int k = 0; k < KMAX; ++k) {
      oc[k] = (unsigned short)ai[k];
      ok[k] = ak[k];
    }
  } else if (blockIdx.x < 2048) {
    int bx = blockIdx.x - 512;
    proj_body(bx >> 8, bx & 255, threadIdx.x, x, wf, projb);
  } else {
    wg_body(blockIdx.x - 2048, threadIdx.x, x, pos, wf, wgtail, bg, h);
  }
}

// ---------------------------------------------------------------------------
// K1a (fallback only): knn_p1 standalone — FROZEN R9 bytes.
// ---------------------------------------------------------------------------
__global__ __launch_bounds__(256) void knn_p1(const float* __restrict__ pos,
                                              unsigned short* __restrict__ cand,
                                              unsigned int* __restrict__ candk) {
  __shared__ float spx[CH * CPAD], spy[CH * CPAD], spz[CH * CPAD], ssq[CH * CPAD];
  __shared__ unsigned int sred[256];
  __shared__ unsigned short sbuf[256 * CAP];
  int b = blockIdx.x >> 6;                       // 64 blocks per batch
  int qbase = (blockIdx.x & 63) * 32;
  const float* pb = pos + (size_t)b * NN * 3;
  for (int t = threadIdx.x; t < NN; t += 256) {
    int a = ((t >> 8) * CPAD) + (t & 255);       // padded SoA address of point t
    float x = pb[t * 3 + 0];
    float y = pb[t * 3 + 1];
    float z = pb[t * 3 + 2];
    spx[a] = x; spy[a] = y; spz[a] = z;
    ssq[a] = sq3(x, y, z);
  }
  __syncthreads();

  int q = qbase + (threadIdx.x >> 3);
  int c = threadIdx.x & 7;
  int qa = ((q >> 8) * CPAD) + (q & 255);
  float px = spx[qa], py = spy[qa], pz = spz[qa];
  float sqq = ssq[qa];

  int abase = c * CPAD;
  int j0 = c * CHSZ;

  unsigned int a0 = 0xFFFFFFFFu, a1 = 0xFFFFFFFFu, a2 = 0xFFFFFFFFu, a3 = 0xFFFFFFFFu;
  for (int jj = 0; jj < CHSZ; ++jj) {
    int a = abase + jj;
    int j = j0 + jj;
    float d2 = d2np(px, py, pz, sqq, spx[a], spy[a], spz[a], ssq[a]);
    unsigned int key = f2key(d2);
    if (j == q) key = 0xFFFFFFFFu;
    if (key < a3) {
      bool c3 = key < a2;
      a3 = c3 ? a2 : key;
      bool c2 = key < a1;
      a2 = c3 ? (c2 ? a1 : key) : a2;
      bool c1 = key < a0;
      a1 = c2 ? (c1 ? a0 : key) : a1;
      a0 = c1 ? key : a0;
    }
  }
  sred[threadIdx.x] = a3;
  __syncthreads();
  if (c == 0) {
    unsigned int m = sred[threadIdx.x];
#pragma unroll
    for (int u = 1; u < 8; ++u) {
      unsigned int v = sred[threadIdx.x + u];
      m = v > m ? v : m;
    }
    sred[threadIdx.x] = m;
  }
  __syncthreads();
  unsigned int T = sred[threadIdx.x & ~7];

  unsigned int ak[KMAX];
  int ai[KMAX];
#pragma unroll
  for (int k = 0; k < KMAX; ++k) { ak[k] = 0xFFFFFFFFu; ai[k] = 0xFFFF; }

  int sbase = threadIdx.x * CAP;
  auto drain = [&](int cnt2) {
    for (int u = 0; u < cnt2; ++u) {
      int jj2 = (int)sbuf[sbase + u];
      int a = abase + jj2;
      int j = j0 + jj2;
      float d2 = d2np(px, py, pz, sqq, spx[a], spy[a], spz[a], ssq[a]);
      unsigned int key = f2key(d2);               // self never buffered
      if (key < ak[KMAX - 1]) {                   // strict: stable ties -> lower j
#pragma unroll
        for (int k = KMAX - 1; k >= 1; --k) {
          bool ck  = key < ak[k];
          bool ckm = key < ak[k - 1];
          unsigned int tk = ckm ? ak[k - 1] : key;
          int          ti = ckm ? ai[k - 1] : j;
          ak[k] = ck ? tk : ak[k];
          ai[k] = ck ? ti : ai[k];
        }
        bool c0b = key < ak[0];
        ak[0] = c0b ? key : ak[0];
        ai[0] = c0b ? j : ai[0];
      }
    }
  };

  int cnt = 0;
  for (int jj = 0; jj < CHSZ; ++jj) {
    int a = abase + jj;
    int j = j0 + jj;
    float d2 = d2np(px, py, pz, sqq, spx[a], spy[a], spz[a], ssq[a]);
    unsigned int key = f2key(d2);
    if (j == q) key = 0xFFFFFFFFu;               // self fails gate (T < max)
    if (key <= T) {
      if (cnt == CAP) { drain(CAP); cnt = 0; }   // rare; preserves j order
      sbuf[sbase + cnt] = (unsigned short)jj;
      ++cnt;
    }
  }
  drain(cnt);

  size_t obase = (((size_t)(b * NN + q)) * CH + c) * KMAX;
  unsigned short* oc = cand + obase;
  unsigned int* ok = candk + obase;
#pragma unroll
  for (int k = 0; k < KMAX; ++k) {
    oc[k] = (unsigned short)ai[k];
    ok[k] = ak[k];
  }
}

// ---------------------------------------------------------------------------
// K1b: KNN phase 2 — 8-way merge. FROZEN R9 bytes.
// ---------------------------------------------------------------------------
__global__ __launch_bounds__(64) void knn_p2(const unsigned int* __restrict__ candk,
                                             const unsigned short* __restrict__ cand,
                                             int* __restrict__ nbr) {
  int q = blockIdx.x * 64 + threadIdx.x;         // global query id (b*NN+n)
  const unsigned int* k8 = candk + (size_t)q * (CH * KMAX);
  const unsigned short* i8 = cand + (size_t)q * (CH * KMAX);

  int head[CH];
  unsigned int hk[CH];
#pragma unroll
  for (int c = 0; c < CH; ++c) {
    head[c] = 0;
    hk[c] = k8[c * KMAX];
  }

  int* onb = nbr + (size_t)q * KMAX;
#pragma unroll
  for (int r = 0; r < KMAX; ++r) {
    int bc = 0;
    unsigned int bk = hk[0];
#pragma unroll
    for (int c = 1; c < CH; ++c) {
      if (hk[c] < bk) { bk = hk[c]; bc = c; }    // strict: ties -> lower c = lower j
    }
    onb[r] = (int)i8[bc * KMAX + head[bc]];
    ++head[bc];
    hk[bc] = (head[bc] < KMAX) ? k8[bc * KMAX + head[bc]] : 0xFFFFFFFFu;
  }
}

// ---------------------------------------------------------------------------
// K-wcvt: 8 weight matrices (f32) -> bf16 B-fragment order. Grid 64 x 256.
// ---------------------------------------------------------------------------
__global__ __launch_bounds__(256) void wcvt(const float* __restrict__ Wa,
                                            const float* __restrict__ Wb,
                                            const float* __restrict__ Wc,
                                            const float* __restrict__ Wgm,
                                            const float* __restrict__ W1m,
                                            unsigned short* __restrict__ wf) {
  int t = blockIdx.x * 256 + threadIdx.x;        // 0 .. 16383
  int lane = t & 63;
  int ks = (t >> 6) & 3;
  int nt = (t >> 8) & 7;
  int z = t >> 11;
  const float* W = (z < 2) ? (Wa + (size_t)z * CC * CC)
                 : (z < 4) ? (Wb + (size_t)(z - 2) * CC * CC)
                 : (z < 6) ? (Wc + (size_t)(z - 4) * CC * CC)
                 : (z == 6) ? Wgm : W1m;
  int n = nt * 16 + (lane & 15);
  int kb = ks * 32 + (lane >> 4) * 8;
  unsigned short* o = wf + (size_t)t * 8;
#pragma unroll
  for (int j = 0; j < 8; ++j)
    o[j] = f2bf(W[(size_t)(kb + j) * CC + n]);
}

// ---------------------------------------------------------------------------
// Fallback-only standalone wrappers for the two MFMA bodies.
// ---------------------------------------------------------------------------
__global__ __launch_bounds__(256) void proj_fly(const float* __restrict__ x,
                                                const unsigned short* __restrict__ wf,
                                                unsigned short* __restrict__ projb) {
  proj_body(blockIdx.z, blockIdx.x, threadIdx.x, x, wf, projb);
}
__global__ __launch_bounds__(256) void wg_fly(const float* __restrict__ x,
                                              const float* __restrict__ pos,
                                              const unsigned short* __restrict__ wf,
                                              const float* __restrict__ wgtail,
                                              const float* __restrict__ bg,
                                              float* __restrict__ h) {
  wg_body(blockIdx.x, threadIdx.x, x, pos, wf, wgtail, bg, h);
}

// ---------------------------------------------------------------------------
// K3: fused attention v3 — 2 channels per lane. One wave = one point
// (64 lanes x 2 ch = 128 ch); block 256 = 4 points; grid M/4.
// Every s/v/t gather is now ONE ushort2 wave-load covering the full 256B row
// (was 2 wave-loads across 2 waves) -> gather instruction count halves.
// Per-channel arithmetic chain identical to R20 -> same numerics class.
// ---------------------------------------------------------------------------
__global__ __launch_bounds__(256) void attn2_kernel(
    const float* __restrict__ pos, const int* __restrict__ nbr,
    const unsigned short* __restrict__ s0, const unsigned short* __restrict__ v0,
    const unsigned short* __restrict__ t0,
    const unsigned short* __restrict__ s1, const unsigned short* __restrict__ v1,
    const unsigned short* __restrict__ t1,
    const float* __restrict__ Wpos, const float* __restrict__ bpos,
    const float* __restrict__ h, unsigned short* __restrict__ hb) {
  int wave = threadIdx.x >> 6;
  int lane = threadIdx.x & 63;
  int p = blockIdx.x * 4 + wave;                 // global point slot
  int b = p & 7;                                 // XCD-locality swizzle
  int n = p >> 3;
  int bn = (b << 11) + n;
  int c0 = lane * 2;                             // this lane's channels: c0, c0+1

  const float* pb = pos + (size_t)b * NN * 3;
  float pix = pb[n * 3 + 0], piy = pb[n * 3 + 1], piz = pb[n * 3 + 2];
  const int* nb = nbr + (size_t)bn * KMAX;

  float2 hin = *(const float2*)(h + (size_t)bn * CC + c0);
  float ht0 = hin.x, ht1 = hin.y;

#pragma unroll
  for (int l = 0; l < 2; ++l) {
    int dil = l + 1;
    const unsigned short* s = l ? s1 : s0;
    const unsigned short* v = l ? v1 : v0;
    const unsigned short* t = l ? t1 : t0;
    const float* Wp = Wpos + (size_t)l * 3 * CC;
    float2 w0v = *(const float2*)(Wp + c0);
    float2 w1v = *(const float2*)(Wp + CC + c0);
    float2 w2v = *(const float2*)(Wp + 2 * CC + c0);
    float2 bpv = *(const float2*)(bpos + (size_t)l * CC + c0);
    ushort2 tc2 = *(const ushort2*)(t + (size_t)bn * CC + c0);
    float tc0 = bf2f(tc2.x), tc1 = bf2f(tc2.y);

    float a0[17], a1[17], d0[17], d1[17];
    float mx0 = -1e30f, mx1 = -1e30f;
#pragma unroll
    for (int j = 0; j < 17; ++j) {
      int idx = (j < 16) ? nb[j * dil] : n;
      float dx = pix - pb[idx * 3 + 0];
      float dy = piy - pb[idx * 3 + 1];
      float dz = piz - pb[idx * 3 + 2];
      d0[j] = dx * w0v.x + dy * w1v.x + dz * w2v.x + bpv.x;
      d1[j] = dx * w0v.y + dy * w1v.y + dz * w2v.y + bpv.y;
      ushort2 sc2 = *(const ushort2*)(s + ((size_t)(b * NN + idx)) * CC + c0);
      float av0 = tc0 - bf2f(sc2.x) + d0[j];
      float av1 = tc1 - bf2f(sc2.y) + d1[j];
      a0[j] = av0; a1[j] = av1;
      mx0 = fmaxf(mx0, av0); mx1 = fmaxf(mx1, av1);
    }
    float sum0 = 0.f, sum1 = 0.f;
#pragma unroll
    for (int j = 0; j < 17; ++j) {
      float w0e = __expf(a0[j] - mx0);
      float w1e = __expf(a1[j] - mx1);
      a0[j] = w0e; a1[j] = w1e;
      sum0 += w0e; sum1 += w1e;
    }
    float inv0 = 1.f / sum0, inv1 = 1.f / sum1;
    float hc0 = 0.f, hc1 = 0.f;
#pragma unroll
    for (int j = 0; j < 17; ++j) {
      int idx = (j < 16) ? nb[j * dil] : n;
      ushort2 vc2 = *(const ushort2*)(v + ((size_t)(b * NN + idx)) * CC + c0);
      hc0 += a0[j] * (bf2f(vc2.x) + d0[j]);
      hc1 += a1[j] * (bf2f(vc2.y) + d1[j]);
    }
    ht0 += hc0 * inv0;
    ht1 += hc1 * inv1;
  }

  ushort2 o = make_ushort2(f2bf(ht0), f2bf(ht1));
  *(ushort2*)(hb + (size_t)bn * CC + c0) = o;
}

// ---------------------------------------------------------------------------
// K4: W1 MFMA + final projection fused (R20 verbatim). Grid M/64 x 256.
// ---------------------------------------------------------------------------
__global__ __launch_bounds__(256) void mfma_w1_final(
    const unsigned short* __restrict__ hb,
    const unsigned short* __restrict__ wz,
    const float* __restrict__ b1,
    const float* __restrict__ W2,
    const float* __restrict__ b2,
    const float* __restrict__ pos,
    float* __restrict__ out) {
  int wave = threadIdx.x >> 6;
  int lane = threadIdx.x & 63;
  int m0 = (blockIdx.x * 4 + wave) * 16;
  int quad = lane >> 4;
  int am = m0 + (lane & 15);

  f32x4 acc[8];
#pragma unroll
  for (int nt = 0; nt < 8; ++nt) acc[nt] = (f32x4){0.f, 0.f, 0.f, 0.f};

#pragma unroll
  for (int ks = 0; ks < 4; ++ks) {
    bf16x8 a = *(const bf16x8*)(hb + (size_t)am * CC + ks * 32 + quad * 8);
#pragma unroll
    for (int nt = 0; nt < 8; ++nt) {
      bf16x8 b = *(const bf16x8*)(wz + (size_t)(((nt * 4 + ks) * 64 + lane) * 8));
      acc[nt] = __builtin_amdgcn_mfma_f32_16x16x32_bf16(a, b, acc[nt], 0, 0, 0);
    }
  }

  int col0 = lane & 15;
  float part[4][3];
#pragma unroll
  for (int r = 0; r < 4; ++r)
#pragma unroll
    for (int d = 0; d < 3; ++d) part[r][d] = 0.f;

#pragma unroll
  for (int nt = 0; nt < 8; ++nt) {
    int col = nt * 16 + col0;
    float bv = b1[col];
    float w20 = W2[col * 3 + 0];
    float w21 = W2[col * 3 + 1];
    float w22 = W2[col * 3 + 2];
#pragma unroll
    for (int r = 0; r < 4; ++r) {
      float gv = acc[nt][r] + bv;
      gv = gv > 0.f ? gv : NEG * gv;
      part[r][0] = fmaf(gv, w20, part[r][0]);
      part[r][1] = fmaf(gv, w21, part[r][1]);
      part[r][2] = fmaf(gv, w22, part[r][2]);
    }
  }

#pragma unroll
  for (int off = 8; off >= 1; off >>= 1) {
#pragma unroll
    for (int r = 0; r < 4; ++r)
#pragma unroll
      for (int d = 0; d < 3; ++d)
        part[r][d] += __shfl_xor(part[r][d], off);
  }

  if (col0 == 0) {
#pragma unroll
    for (int r = 0; r < 4; ++r) {
      int m = m0 + quad * 4 + r;
#pragma unroll
      for (int d = 0; d < 3; ++d)
        out[(size_t)m * 3 + d] = part[r][d] + b2[d] + pos[(size_t)m * 3 + d];
    }
  }
}

extern "C" void kernel_launch(void* const* d_in, const int* in_sizes, int n_in,
                              void* d_out, int out_size, void* d_ws, size_t ws_size,
                              hipStream_t stream) {
  const float* x     = (const float*)d_in[0];
  const float* pos   = (const float*)d_in[1];
  const float* W_lin = (const float*)d_in[2];
  const float* W_src = (const float*)d_in[3];
  const float* W_dst = (const float*)d_in[4];
  const float* W_pos = (const float*)d_in[5];
  const float* b_pos = (const float*)d_in[6];
  const float* Wg    = (const float*)d_in[7];
  const float* bg    = (const float*)d_in[8];
  const float* W1    = (const float*)d_in[9];
  const float* b1    = (const float*)d_in[10];
  const float* W2    = (const float*)d_in[11];
  const float* b2    = (const float*)d_in[12];
  float* out = (float*)d_out;

  const size_t M = (size_t)BB * NN;        // 16384
  const size_t MC = M * CC;                // 2,097,152

  // Layout (R17-21 proven offsets): nbr 2MB | cand 8.39MB | fb region:
  //   projb (bf16, fb[0..3MC))  s0,s1,v0,v1,t0,t1
  //   candk (u32,  fb[3MC..5MC))
  //   h     (f32,  fb[5MC..6MC))
  // hb at ws+BASE (4MB) | wf at ws+BASE+4MB (256KB).
  char* ws = (char*)d_ws;
  int* nbr = (int*)ws;
  unsigned short* cand = (unsigned short*)(ws + M * KMAX * sizeof(int));
  float* fb = (float*)(ws + M * KMAX * sizeof(int) + M * CH * KMAX * sizeof(unsigned short));
  unsigned short* projb = (unsigned short*)fb;
  unsigned short* sb0 = projb + 0 * MC;
  unsigned short* sb1 = projb + 1 * MC;
  unsigned short* vb0 = projb + 2 * MC;
  unsigned short* vb1 = projb + 3 * MC;
  unsigned short* tb0 = projb + 4 * MC;
  unsigned short* tb1 = projb + 5 * MC;
  unsigned int* candk = (unsigned int*)(fb + 3 * MC);
  float* h = fb + 5 * MC;

  const size_t BASE = M * KMAX * sizeof(int) + M * CH * KMAX * sizeof(unsigned short)
                    + 8 * MC * sizeof(float);                 // proven offset
  const size_t XB_BYTES = MC * sizeof(unsigned short);        // 4 MB (hb slot)
  const size_t WF_BYTES = 8 * 16384 * sizeof(unsigned short); // 256 KB
  const size_t FRAG = (size_t)(8 * 4 * 64 * 8);               // bf16 elems per weight
  bool fused_ok = ws_size >= BASE + XB_BYTES + WF_BYTES;

  if (fused_ok) {
    unsigned short* hb = (unsigned short*)(ws + BASE);
    unsigned short* wf = (unsigned short*)(ws + BASE + XB_BYTES);

    // 1. weight fragments (tiny)
    wcvt<<<64, 256, 0, stream>>>(W_src, W_lin, W_dst, Wg, W1, wf);
    // 2. knn_p1 [0,512) + 6-proj [512,2048) + Wg-epi [2048,2304), x on-the-fly
    fused_front<<<2304, 256, 0, stream>>>(pos, cand, candk, x, wf, projb,
                                          Wg + 128 * CC, bg, h);
    // 3. merge
    knn_p2<<<256, 64, 0, stream>>>(candk, cand, nbr);
    // 4. attention v3 (2 ch/lane, 1 wave/point); writes hb = bf16(h_out)
    attn2_kernel<<<M / 4, 256, 0, stream>>>(pos, nbr, sb0, vb0, tb0,
                                            sb1, vb1, tb1, W_pos, b_pos, h, hb);
    // 5. g = leaky(h@W1+b1) via MFMA, then W2 reduce + b2 + pos, fused
    mfma_w1_final<<<M / 64, 256, 0, stream>>>(hb, wf + 7 * FRAG, b1,
                                              W2, b2, pos, out);
  } else {
    // Fallback: sequential, same numerics. hb/wf alias cand (dead after p2).
    unsigned short* hb = cand;
    unsigned short* wf = cand + MC;
    knn_p1<<<512, 256, 0, stream>>>(pos, cand, candk);
    knn_p2<<<256, 64, 0, stream>>>(candk, cand, nbr);
    wcvt<<<64, 256, 0, stream>>>(W_src, W_lin, W_dst, Wg, W1, wf);
    proj_fly<<<dim3(256, 1, 6), 256, 0, stream>>>(x, wf, projb);
    wg_fly<<<256, 256, 0, stream>>>(x, pos, wf, Wg + 128 * CC, bg, h);
    attn2_kernel<<<M / 4, 256, 0, stream>>>(pos, nbr, sb0, vb0, tb0,
                                            sb1, vb1, tb1, W_pos, b_pos, h, hb);
    mfma_w1_final<<<M / 64, 256, 0, stream>>>(hb, wf + 7 * FRAG, b1,
                                              W2, b2, pos, out);
  }
}

// Round 23
// 235.221 us; speedup vs baseline: 1.0297x; 1.0297x over previous
//
#include <hip/hip_runtime.h>

#define BB 8
#define NN 2048
#define CC 128
#define KMAX 32
#define NEG 0.2f
#define CH 8
#define CHSZ (NN / CH)   // 256
#define CPAD 260         // chunk stride in LDS: (260*c+jj)%32 = (4c+jj)%32 -> 8 distinct banks
#define CAP 32           // per-thread candidate buffer (drain-on-full keeps j order)

using bf16x8 = __attribute__((ext_vector_type(8))) short;  // 8 bf16 (4 VGPRs)
using f32x4  = __attribute__((ext_vector_type(4))) float;  // 4 fp32

// Map f32 to a u32 whose unsigned order == float order (handles negatives).
__device__ __forceinline__ unsigned int f2key(float f) {
  unsigned int b = __float_as_uint(f);
  return (b & 0x80000000u) ? ~b : (b | 0x80000000u);
}

// np-exact f32 squared norm: fl(fl(x^2+y^2)+z^2), no FMA contraction.
__device__ __forceinline__ float sq3(float x, float y, float z) {
  return __fadd_rn(__fadd_rn(__fmul_rn(x, x), __fmul_rn(y, y)), __fmul_rn(z, z));
}

// np-exact f32 distance key: d2 = fl( fl(sq_i+sq_j) - fl(2*dot) ).
__device__ __forceinline__ float d2np(float px, float py, float pz, float sqq,
                                      float qx, float qy, float qz, float sqj) {
  float dot = __fmaf_rn(pz, qz, __fmaf_rn(py, qy, __fmul_rn(px, qx)));
  return __fsub_rn(__fadd_rn(sqq, sqj), __fmul_rn(2.0f, dot));
}

// f32 -> bf16 (round to nearest even), finite inputs.
__device__ __forceinline__ unsigned short f2bf(float f) {
  unsigned int u = __float_as_uint(f);
  return (unsigned short)((u + 0x7fffu + ((u >> 16) & 1u)) >> 16);
}
// bf16 -> f32, exact.
__device__ __forceinline__ float bf2f(unsigned short u) {
  return __uint_as_float(((unsigned int)u) << 16);
}

// 8 consecutive f32 -> bf16x8 A-fragment (bit-identical to the old cvt_x+load).
__device__ __forceinline__ bf16x8 cvt8(const float* __restrict__ p) {
  float4 a = *(const float4*)(p);
  float4 b = *(const float4*)(p + 4);
  bf16x8 r;
  r[0] = (short)f2bf(a.x); r[1] = (short)f2bf(a.y);
  r[2] = (short)f2bf(a.z); r[3] = (short)f2bf(a.w);
  r[4] = (short)f2bf(b.x); r[5] = (short)f2bf(b.y);
  r[6] = (short)f2bf(b.z); r[7] = (short)f2bf(b.w);
  return r;
}

// ---------------------------------------------------------------------------
// 6-proj MFMA body (on-the-fly x conversion), bf16 out.
// ---------------------------------------------------------------------------
__device__ __forceinline__ void proj_body(int z, int mx, int tid,
                                          const float* __restrict__ x,
                                          const unsigned short* __restrict__ wf,
                                          unsigned short* __restrict__ projb) {
  unsigned short* out = projb + (size_t)z * ((size_t)BB * NN * CC);
  int wave = tid >> 6;
  int lane = tid & 63;
  int m0 = (mx * 4 + wave) * 16;
  int quad = lane >> 4;
  int am = m0 + (lane & 15);

  f32x4 acc[8];
#pragma unroll
  for (int nt = 0; nt < 8; ++nt) acc[nt] = (f32x4){0.f, 0.f, 0.f, 0.f};

  const unsigned short* wz = wf + (size_t)z * (8 * 4 * 64 * 8);
#pragma unroll
  for (int ks = 0; ks < 4; ++ks) {
    bf16x8 a = cvt8(x + (size_t)am * CC + ks * 32 + quad * 8);
#pragma unroll
    for (int nt = 0; nt < 8; ++nt) {
      bf16x8 bfr = *(const bf16x8*)(wz + (size_t)(((nt * 4 + ks) * 64 + lane) * 8));
      acc[nt] = __builtin_amdgcn_mfma_f32_16x16x32_bf16(a, bfr, acc[nt], 0, 0, 0);
    }
  }

  int col0 = lane & 15;
#pragma unroll
  for (int nt = 0; nt < 8; ++nt)
#pragma unroll
    for (int r = 0; r < 4; ++r)
      out[(size_t)(m0 + quad * 4 + r) * CC + nt * 16 + col0] = f2bf(acc[nt][r]);
}

// ---------------------------------------------------------------------------
// Wg epilogue MFMA body (on-the-fly x conversion), f32 h out.
// ---------------------------------------------------------------------------
__device__ __forceinline__ void wg_body(int mx, int tid,
                                        const float* __restrict__ x,
                                        const float* __restrict__ pos,
                                        const unsigned short* __restrict__ wf,
                                        const float* __restrict__ wgtail,
                                        const float* __restrict__ bg,
                                        float* __restrict__ h) {
  int wave = tid >> 6;
  int lane = tid & 63;
  int m0 = (mx * 4 + wave) * 16;
  int quad = lane >> 4;
  int am = m0 + (lane & 15);

  f32x4 acc[8];
#pragma unroll
  for (int nt = 0; nt < 8; ++nt) acc[nt] = (f32x4){0.f, 0.f, 0.f, 0.f};

  const unsigned short* wz = wf + (size_t)6 * (8 * 4 * 64 * 8);
#pragma unroll
  for (int ks = 0; ks < 4; ++ks) {
    bf16x8 a = cvt8(x + (size_t)am * CC + ks * 32 + quad * 8);
#pragma unroll
    for (int nt = 0; nt < 8; ++nt) {
      bf16x8 b = *(const bf16x8*)(wz + (size_t)(((nt * 4 + ks) * 64 + lane) * 8));
      acc[nt] = __builtin_amdgcn_mfma_f32_16x16x32_bf16(a, b, acc[nt], 0, 0, 0);
    }
  }

  float posr[4][3];
#pragma unroll
  for (int r = 0; r < 4; ++r) {
    int m = m0 + quad * 4 + r;
    posr[r][0] = pos[m * 3 + 0];
    posr[r][1] = pos[m * 3 + 1];
    posr[r][2] = pos[m * 3 + 2];
  }

  int col0 = lane & 15;
#pragma unroll
  for (int nt = 0; nt < 8; ++nt) {
    int col = nt * 16 + col0;
    float bv = bg[col];
    float t0 = wgtail[col];
    float t1 = wgtail[CC + col];
    float t2 = wgtail[2 * CC + col];
#pragma unroll
    for (int r = 0; r < 4; ++r) {
      float v = acc[nt][r] + bv
              + posr[r][0] * t0 + posr[r][1] * t1 + posr[r][2] * t2;
      v = v > 0.f ? v : NEG * v;
      h[(size_t)(m0 + quad * 4 + r) * CC + col] = v;
    }
  }
}

// ---------------------------------------------------------------------------
// FUSED FRONT: blocks [0,512) = knn_p1 (FROZEN R9 body); blocks [512,2048) =
// 6-proj bf16 MFMA; blocks [2048,2304) = Wg epilogue MFMA.
// ---------------------------------------------------------------------------
__global__ __launch_bounds__(256) void fused_front(
    const float* __restrict__ pos,
    unsigned short* __restrict__ cand,
    unsigned int* __restrict__ candk,
    const float* __restrict__ x,
    const unsigned short* __restrict__ wf,
    unsigned short* __restrict__ projb,
    const float* __restrict__ wgtail,
    const float* __restrict__ bg,
    float* __restrict__ h) {
  __shared__ float spx[CH * CPAD], spy[CH * CPAD], spz[CH * CPAD], ssq[CH * CPAD];
  __shared__ unsigned int sred[256];
  __shared__ unsigned short sbuf[256 * CAP];

  if (blockIdx.x < 512) {
    // ---------------- knn_p1: FROZEN R9 body. Do not touch. ----------------
    int b = blockIdx.x >> 6;                       // 64 blocks per batch
    int qbase = (blockIdx.x & 63) * 32;
    const float* pb = pos + (size_t)b * NN * 3;
    for (int t = threadIdx.x; t < NN; t += 256) {
      int a = ((t >> 8) * CPAD) + (t & 255);       // padded SoA address of point t
      float xx = pb[t * 3 + 0];
      float yy = pb[t * 3 + 1];
      float zz = pb[t * 3 + 2];
      spx[a] = xx; spy[a] = yy; spz[a] = zz;
      ssq[a] = sq3(xx, yy, zz);
    }
    __syncthreads();

    int q = qbase + (threadIdx.x >> 3);
    int c = threadIdx.x & 7;
    int qa = ((q >> 8) * CPAD) + (q & 255);
    float px = spx[qa], py = spy[qa], pz = spz[qa];
    float sqq = ssq[qa];

    int abase = c * CPAD;
    int j0 = c * CHSZ;

    unsigned int a0 = 0xFFFFFFFFu, a1 = 0xFFFFFFFFu, a2 = 0xFFFFFFFFu, a3 = 0xFFFFFFFFu;
    for (int jj = 0; jj < CHSZ; ++jj) {
      int a = abase + jj;
      int j = j0 + jj;
      float d2 = d2np(px, py, pz, sqq, spx[a], spy[a], spz[a], ssq[a]);
      unsigned int key = f2key(d2);
      if (j == q) key = 0xFFFFFFFFu;
      if (key < a3) {
        bool c3 = key < a2;
        a3 = c3 ? a2 : key;
        bool c2 = key < a1;
        a2 = c3 ? (c2 ? a1 : key) : a2;
        bool c1 = key < a0;
        a1 = c2 ? (c1 ? a0 : key) : a1;
        a0 = c1 ? key : a0;
      }
    }
    sred[threadIdx.x] = a3;
    __syncthreads();
    if (c == 0) {
      unsigned int m = sred[threadIdx.x];
#pragma unroll
      for (int u = 1; u < 8; ++u) {
        unsigned int v = sred[threadIdx.x + u];
        m = v > m ? v : m;
      }
      sred[threadIdx.x] = m;
    }
    __syncthreads();
    unsigned int T = sred[threadIdx.x & ~7];

    unsigned int ak[KMAX];
    int ai[KMAX];
#pragma unroll
    for (int k = 0; k < KMAX; ++k) { ak[k] = 0xFFFFFFFFu; ai[k] = 0xFFFF; }

    int sbase = threadIdx.x * CAP;
    auto drain = [&](int cnt2) {
      for (int u = 0; u < cnt2; ++u) {
        int jj2 = (int)sbuf[sbase + u];
        int a = abase + jj2;
        int j = j0 + jj2;
        float d2 = d2np(px, py, pz, sqq, spx[a], spy[a], spz[a], ssq[a]);
        unsigned int key = f2key(d2);               // self never buffered
        if (key < ak[KMAX - 1]) {                   // strict: stable ties -> lower j
#pragma unroll
          for (int k = KMAX - 1; k >= 1; --k) {
            bool ck  = key < ak[k];
            bool ckm = key < ak[k - 1];
            unsigned int tk = ckm ? ak[k - 1] : key;
            int          ti = ckm ? ai[k - 1] : j;
            ak[k] = ck ? tk : ak[k];
            ai[k] = ck ? ti : ai[k];
          }
          bool c0b = key < ak[0];
          ak[0] = c0b ? key : ak[0];
          ai[0] = c0b ? j : ai[0];
        }
      }
    };

    int cnt = 0;
    for (int jj = 0; jj < CHSZ; ++jj) {
      int a = abase + jj;
      int j = j0 + jj;
      float d2 = d2np(px, py, pz, sqq, spx[a], spy[a], spz[a], ssq[a]);
      unsigned int key = f2key(d2);
      if (j == q) key = 0xFFFFFFFFu;               // self fails gate (T < max)
      if (key <= T) {
        if (cnt == CAP) { drain(CAP); cnt = 0; }   // rare; preserves j order
        sbuf[sbase + cnt] = (unsigned short)jj;
        ++cnt;
      }
    }
    drain(cnt);

    size_t obase = (((size_t)(b * NN + q)) * CH + c) * KMAX;
    unsigned short* oc = cand + obase;
    unsigned int* ok = candk + obase;
#pragma unroll
    for (int k = 0; k < KMAX; ++k) {
      oc[k] = (unsigned short)ai[k];
      ok[k] = ak[k];
    }
  } else if (blockIdx.x < 2048) {
    int bx = blockIdx.x - 512;
    proj_body(bx >> 8, bx & 255, threadIdx.x, x, wf, projb);
  } else {
    wg_body(blockIdx.x - 2048, threadIdx.x, x, pos, wf, wgtail, bg, h);
  }
}

// ---------------------------------------------------------------------------
// K1a (fallback only): knn_p1 standalone — FROZEN R9 bytes.
// ---------------------------------------------------------------------------
__global__ __launch_bounds__(256) void knn_p1(const float* __restrict__ pos,
                                              unsigned short* __restrict__ cand,
                                              unsigned int* __restrict__ candk) {
  __shared__ float spx[CH * CPAD], spy[CH * CPAD], spz[CH * CPAD], ssq[CH * CPAD];
  __shared__ unsigned int sred[256];
  __shared__ unsigned short sbuf[256 * CAP];
  int b = blockIdx.x >> 6;                       // 64 blocks per batch
  int qbase = (blockIdx.x & 63) * 32;
  const float* pb = pos + (size_t)b * NN * 3;
  for (int t = threadIdx.x; t < NN; t += 256) {
    int a = ((t >> 8) * CPAD) + (t & 255);       // padded SoA address of point t
    float x = pb[t * 3 + 0];
    float y = pb[t * 3 + 1];
    float z = pb[t * 3 + 2];
    spx[a] = x; spy[a] = y; spz[a] = z;
    ssq[a] = sq3(x, y, z);
  }
  __syncthreads();

  int q = qbase + (threadIdx.x >> 3);
  int c = threadIdx.x & 7;
  int qa = ((q >> 8) * CPAD) + (q & 255);
  float px = spx[qa], py = spy[qa], pz = spz[qa];
  float sqq = ssq[qa];

  int abase = c * CPAD;
  int j0 = c * CHSZ;

  unsigned int a0 = 0xFFFFFFFFu, a1 = 0xFFFFFFFFu, a2 = 0xFFFFFFFFu, a3 = 0xFFFFFFFFu;
  for (int jj = 0; jj < CHSZ; ++jj) {
    int a = abase + jj;
    int j = j0 + jj;
    float d2 = d2np(px, py, pz, sqq, spx[a], spy[a], spz[a], ssq[a]);
    unsigned int key = f2key(d2);
    if (j == q) key = 0xFFFFFFFFu;
    if (key < a3) {
      bool c3 = key < a2;
      a3 = c3 ? a2 : key;
      bool c2 = key < a1;
      a2 = c3 ? (c2 ? a1 : key) : a2;
      bool c1 = key < a0;
      a1 = c2 ? (c1 ? a0 : key) : a1;
      a0 = c1 ? key : a0;
    }
  }
  sred[threadIdx.x] = a3;
  __syncthreads();
  if (c == 0) {
    unsigned int m = sred[threadIdx.x];
#pragma unroll
    for (int u = 1; u < 8; ++u) {
      unsigned int v = sred[threadIdx.x + u];
      m = v > m ? v : m;
    }
    sred[threadIdx.x] = m;
  }
  __syncthreads();
  unsigned int T = sred[threadIdx.x & ~7];

  unsigned int ak[KMAX];
  int ai[KMAX];
#pragma unroll
  for (int k = 0; k < KMAX; ++k) { ak[k] = 0xFFFFFFFFu; ai[k] = 0xFFFF; }

  int sbase = threadIdx.x * CAP;
  auto drain = [&](int cnt2) {
    for (int u = 0; u < cnt2; ++u) {
      int jj2 = (int)sbuf[sbase + u];
      int a = abase + jj2;
      int j = j0 + jj2;
      float d2 = d2np(px, py, pz, sqq, spx[a], spy[a], spz[a], ssq[a]);
      unsigned int key = f2key(d2);               // self never buffered
      if (key < ak[KMAX - 1]) {                   // strict: stable ties -> lower j
#pragma unroll
        for (int k = KMAX - 1; k >= 1; --k) {
          bool ck  = key < ak[k];
          bool ckm = key < ak[k - 1];
          unsigned int tk = ckm ? ak[k - 1] : key;
          int          ti = ckm ? ai[k - 1] : j;
          ak[k] = ck ? tk : ak[k];
          ai[k] = ck ? ti : ai[k];
        }
        bool c0b = key < ak[0];
        ak[0] = c0b ? key : ak[0];
        ai[0] = c0b ? j : ai[0];
      }
    }
  };

  int cnt = 0;
  for (int jj = 0; jj < CHSZ; ++jj) {
    int a = abase + jj;
    int j = j0 + jj;
    float d2 = d2np(px, py, pz, sqq, spx[a], spy[a], spz[a], ssq[a]);
    unsigned int key = f2key(d2);
    if (j == q) key = 0xFFFFFFFFu;               // self fails gate (T < max)
    if (key <= T) {
      if (cnt == CAP) { drain(CAP); cnt = 0; }   // rare; preserves j order
      sbuf[sbase + cnt] = (unsigned short)jj;
      ++cnt;
    }
  }
  drain(cnt);

  size_t obase = (((size_t)(b * NN + q)) * CH + c) * KMAX;
  unsigned short* oc = cand + obase;
  unsigned int* ok = candk + obase;
#pragma unroll
  for (int k = 0; k < KMAX; ++k) {
    oc[k] = (unsigned short)ai[k];
    ok[k] = ak[k];
  }
}

// ---------------------------------------------------------------------------
// K1b: KNN phase 2 — 8-way merge. FROZEN R9 bytes.
// ---------------------------------------------------------------------------
__global__ __launch_bounds__(64) void knn_p2(const unsigned int* __restrict__ candk,
                                             const unsigned short* __restrict__ cand,
                                             int* __restrict__ nbr) {
  int q = blockIdx.x * 64 + threadIdx.x;         // global query id (b*NN+n)
  const unsigned int* k8 = candk + (size_t)q * (CH * KMAX);
  const unsigned short* i8 = cand + (size_t)q * (CH * KMAX);

  int head[CH];
  unsigned int hk[CH];
#pragma unroll
  for (int c = 0; c < CH; ++c) {
    head[c] = 0;
    hk[c] = k8[c * KMAX];
  }

  int* onb = nbr + (size_t)q * KMAX;
#pragma unroll
  for (int r = 0; r < KMAX; ++r) {
    int bc = 0;
    unsigned int bk = hk[0];
#pragma unroll
    for (int c = 1; c < CH; ++c) {
      if (hk[c] < bk) { bk = hk[c]; bc = c; }    // strict: ties -> lower c = lower j
    }
    onb[r] = (int)i8[bc * KMAX + head[bc]];
    ++head[bc];
    hk[bc] = (head[bc] < KMAX) ? k8[bc * KMAX + head[bc]] : 0xFFFFFFFFu;
  }
}

// ---------------------------------------------------------------------------
// K-wcvt: 8 weight matrices (f32) -> bf16 B-fragment order. Grid 64 x 256.
// ---------------------------------------------------------------------------
__global__ __launch_bounds__(256) void wcvt(const float* __restrict__ Wa,
                                            const float* __restrict__ Wb,
                                            const float* __restrict__ Wc,
                                            const float* __restrict__ Wgm,
                                            const float* __restrict__ W1m,
                                            unsigned short* __restrict__ wf) {
  int t = blockIdx.x * 256 + threadIdx.x;        // 0 .. 16383
  int lane = t & 63;
  int ks = (t >> 6) & 3;
  int nt = (t >> 8) & 7;
  int z = t >> 11;
  const float* W = (z < 2) ? (Wa + (size_t)z * CC * CC)
                 : (z < 4) ? (Wb + (size_t)(z - 2) * CC * CC)
                 : (z < 6) ? (Wc + (size_t)(z - 4) * CC * CC)
                 : (z == 6) ? Wgm : W1m;
  int n = nt * 16 + (lane & 15);
  int kb = ks * 32 + (lane >> 4) * 8;
  unsigned short* o = wf + (size_t)t * 8;
#pragma unroll
  for (int j = 0; j < 8; ++j)
    o[j] = f2bf(W[(size_t)(kb + j) * CC + n]);
}

// ---------------------------------------------------------------------------
// Fallback-only standalone wrappers for the two MFMA bodies.
// ---------------------------------------------------------------------------
__global__ __launch_bounds__(256) void proj_fly(const float* __restrict__ x,
                                                const unsigned short* __restrict__ wf,
                                                unsigned short* __restrict__ projb) {
  proj_body(blockIdx.z, blockIdx.x, threadIdx.x, x, wf, projb);
}
__global__ __launch_bounds__(256) void wg_fly(const float* __restrict__ x,
                                              const float* __restrict__ pos,
                                              const unsigned short* __restrict__ wf,
                                              const float* __restrict__ wgtail,
                                              const float* __restrict__ bg,
                                              float* __restrict__ h) {
  wg_body(blockIdx.x, threadIdx.x, x, pos, wf, wgtail, bg, h);
}

// ---------------------------------------------------------------------------
// K3: fused attention (R19/R20-proven) — bf16 s/v/t gathers, __expf, batch
// swizzle, writes hb (bf16). Block 128 = one point's channels.
// ---------------------------------------------------------------------------
__global__ __launch_bounds__(128) void attn2_kernel(
    const float* __restrict__ pos, const int* __restrict__ nbr,
    const unsigned short* __restrict__ s0, const unsigned short* __restrict__ v0,
    const unsigned short* __restrict__ t0,
    const unsigned short* __restrict__ s1, const unsigned short* __restrict__ v1,
    const unsigned short* __restrict__ t1,
    const float* __restrict__ Wpos, const float* __restrict__ bpos,
    const float* __restrict__ h, unsigned short* __restrict__ hb) {
  int b = blockIdx.x & 7;                        // XCD-locality swizzle
  int n = blockIdx.x >> 3;
  int bn = (b << 11) + n;
  int c = threadIdx.x;

  const float* pb = pos + (size_t)b * NN * 3;
  float pix = pb[n * 3 + 0], piy = pb[n * 3 + 1], piz = pb[n * 3 + 2];
  const int* nb = nbr + (size_t)bn * KMAX;

  float ht = h[(size_t)bn * CC + c];             // h_in (Wg output, f32)

#pragma unroll
  for (int l = 0; l < 2; ++l) {
    int dil = l + 1;
    const unsigned short* s = l ? s1 : s0;
    const unsigned short* v = l ? v1 : v0;
    const unsigned short* t = l ? t1 : t0;
    const float* Wp = Wpos + (size_t)l * 3 * CC;
    float w0 = Wp[c], w1 = Wp[CC + c], w2 = Wp[2 * CC + c];
    float bp = bpos[(size_t)l * CC + c];
    float tc = bf2f(t[(size_t)bn * CC + c]);

    float alpha[17], del[17];
    float mx = -1e30f;
#pragma unroll
    for (int j = 0; j < 17; ++j) {
      int idx = (j < 16) ? nb[j * dil] : n;
      float dx = pix - pb[idx * 3 + 0];
      float dy = piy - pb[idx * 3 + 1];
      float dz = piz - pb[idx * 3 + 2];
      float d = dx * w0 + dy * w1 + dz * w2 + bp;
      del[j] = d;
      float sc = bf2f(s[((size_t)(b * NN + idx)) * CC + c]);
      float a = tc - sc + d;
      alpha[j] = a;
      mx = fmaxf(mx, a);
    }
    float sum = 0.f;
#pragma unroll
    for (int j = 0; j < 17; ++j) {
      float w = __expf(alpha[j] - mx);
      alpha[j] = w;
      sum += w;
    }
    float inv = 1.f / sum;
    float hc = 0.f;
#pragma unroll
    for (int j = 0; j < 17; ++j) {
      int idx = (j < 16) ? nb[j * dil] : n;
      float vc = bf2f(v[((size_t)(b * NN + idx)) * CC + c]);
      hc += alpha[j] * (vc + del[j]);
    }
    ht += hc * inv;
  }

  hb[(size_t)bn * CC + c] = f2bf(ht);
}

// ---------------------------------------------------------------------------
// K4: W1 MFMA + final projection fused. Grid M/64 x 256.
// ---------------------------------------------------------------------------
__global__ __launch_bounds__(256) void mfma_w1_final(
    const unsigned short* __restrict__ hb,
    const unsigned short* __restrict__ wz,
    const float* __restrict__ b1,
    const float* __restrict__ W2,
    const float* __restrict__ b2,
    const float* __restrict__ pos,
    float* __restrict__ out) {
  int wave = threadIdx.x >> 6;
  int lane = threadIdx.x & 63;
  int m0 = (blockIdx.x * 4 + wave) * 16;
  int quad = lane >> 4;
  int am = m0 + (lane & 15);

  f32x4 acc[8];
#pragma unroll
  for (int nt = 0; nt < 8; ++nt) acc[nt] = (f32x4){0.f, 0.f, 0.f, 0.f};

#pragma unroll
  for (int ks = 0; ks < 4; ++ks) {
    bf16x8 a = *(const bf16x8*)(hb + (size_t)am * CC + ks * 32 + quad * 8);
#pragma unroll
    for (int nt = 0; nt < 8; ++nt) {
      bf16x8 b = *(const bf16x8*)(wz + (size_t)(((nt * 4 + ks) * 64 + lane) * 8));
      acc[nt] = __builtin_amdgcn_mfma_f32_16x16x32_bf16(a, b, acc[nt], 0, 0, 0);
    }
  }

  int col0 = lane & 15;
  float part[4][3];
#pragma unroll
  for (int r = 0; r < 4; ++r)
#pragma unroll
    for (int d = 0; d < 3; ++d) part[r][d] = 0.f;

#pragma unroll
  for (int nt = 0; nt < 8; ++nt) {
    int col = nt * 16 + col0;
    float bv = b1[col];
    float w20 = W2[col * 3 + 0];
    float w21 = W2[col * 3 + 1];
    float w22 = W2[col * 3 + 2];
#pragma unroll
    for (int r = 0; r < 4; ++r) {
      float gv = acc[nt][r] + bv;
      gv = gv > 0.f ? gv : NEG * gv;
      part[r][0] = fmaf(gv, w20, part[r][0]);
      part[r][1] = fmaf(gv, w21, part[r][1]);
      part[r][2] = fmaf(gv, w22, part[r][2]);
    }
  }

#pragma unroll
  for (int off = 8; off >= 1; off >>= 1) {
#pragma unroll
    for (int r = 0; r < 4; ++r)
#pragma unroll
      for (int d = 0; d < 3; ++d)
        part[r][d] += __shfl_xor(part[r][d], off);
  }

  if (col0 == 0) {
#pragma unroll
    for (int r = 0; r < 4; ++r) {
      int m = m0 + quad * 4 + r;
#pragma unroll
      for (int d = 0; d < 3; ++d)
        out[(size_t)m * 3 + d] = part[r][d] + b2[d] + pos[(size_t)m * 3 + d];
    }
  }
}

extern "C" void kernel_launch(void* const* d_in, const int* in_sizes, int n_in,
                              void* d_out, int out_size, void* d_ws, size_t ws_size,
                              hipStream_t stream) {
  const float* x     = (const float*)d_in[0];
  const float* pos   = (const float*)d_in[1];
  const float* W_lin = (const float*)d_in[2];
  const float* W_src = (const float*)d_in[3];
  const float* W_dst = (const float*)d_in[4];
  const float* W_pos = (const float*)d_in[5];
  const float* b_pos = (const float*)d_in[6];
  const float* Wg    = (const float*)d_in[7];
  const float* bg    = (const float*)d_in[8];
  const float* W1    = (const float*)d_in[9];
  const float* b1    = (const float*)d_in[10];
  const float* W2    = (const float*)d_in[11];
  const float* b2    = (const float*)d_in[12];
  float* out = (float*)d_out;

  const size_t M = (size_t)BB * NN;        // 16384
  const size_t MC = M * CC;                // 2,097,152

  // Layout (R17-20 proven offsets): nbr 2MB | cand 8.39MB | fb region:
  //   projb (bf16, fb[0..3MC))  s0,s1,v0,v1,t0,t1
  //   candk (u32,  fb[3MC..5MC))
  //   h     (f32,  fb[5MC..6MC))
  // hb at ws+BASE (4MB) | wf at ws+BASE+4MB (256KB).
  char* ws = (char*)d_ws;
  int* nbr = (int*)ws;
  unsigned short* cand = (unsigned short*)(ws + M * KMAX * sizeof(int));
  float* fb = (float*)(ws + M * KMAX * sizeof(int) + M * CH * KMAX * sizeof(unsigned short));
  unsigned short* projb = (unsigned short*)fb;
  unsigned short* sb0 = projb + 0 * MC;
  unsigned short* sb1 = projb + 1 * MC;
  unsigned short* vb0 = projb + 2 * MC;
  unsigned short* vb1 = projb + 3 * MC;
  unsigned short* tb0 = projb + 4 * MC;
  unsigned short* tb1 = projb + 5 * MC;
  unsigned int* candk = (unsigned int*)(fb + 3 * MC);
  float* h = fb + 5 * MC;

  const size_t BASE = M * KMAX * sizeof(int) + M * CH * KMAX * sizeof(unsigned short)
                    + 8 * MC * sizeof(float);                 // proven offset
  const size_t XB_BYTES = MC * sizeof(unsigned short);        // 4 MB (hb slot)
  const size_t WF_BYTES = 8 * 16384 * sizeof(unsigned short); // 256 KB
  const size_t FRAG = (size_t)(8 * 4 * 64 * 8);               // bf16 elems per weight
  bool fused_ok = ws_size >= BASE + XB_BYTES + WF_BYTES;

  if (fused_ok) {
    unsigned short* hb = (unsigned short*)(ws + BASE);
    unsigned short* wf = (unsigned short*)(ws + BASE + XB_BYTES);

    // 1. weight fragments (tiny)
    wcvt<<<64, 256, 0, stream>>>(W_src, W_lin, W_dst, Wg, W1, wf);
    // 2. knn_p1 [0,512) + 6-proj [512,2048) + Wg-epi [2048,2304), x on-the-fly
    fused_front<<<2304, 256, 0, stream>>>(pos, cand, candk, x, wf, projb,
                                          Wg + 128 * CC, bg, h);
    // 3. merge
    knn_p2<<<256, 64, 0, stream>>>(candk, cand, nbr);
    // 4. attention (R20-proven 128-thread form); writes hb = bf16(h_out)
    attn2_kernel<<<M, 128, 0, stream>>>(pos, nbr, sb0, vb0, tb0,
                                        sb1, vb1, tb1, W_pos, b_pos, h, hb);
    // 5. g = leaky(h@W1+b1) via MFMA, then W2 reduce + b2 + pos, fused
    mfma_w1_final<<<M / 64, 256, 0, stream>>>(hb, wf + 7 * FRAG, b1,
                                              W2, b2, pos, out);
  } else {
    // Fallback: sequential, same numerics. hb/wf alias cand (dead after p2).
    unsigned short* hb = cand;
    unsigned short* wf = cand + MC;
    knn_p1<<<512, 256, 0, stream>>>(pos, cand, candk);
    knn_p2<<<256, 64, 0, stream>>>(candk, cand, nbr);
    wcvt<<<64, 256, 0, stream>>>(W_src, W_lin, W_dst, Wg, W1, wf);
    proj_fly<<<dim3(256, 1, 6), 256, 0, stream>>>(x, wf, projb);
    wg_fly<<<256, 256, 0, stream>>>(x, pos, wf, Wg + 128 * CC, bg, h);
    attn2_kernel<<<M, 128, 0, stream>>>(pos, nbr, sb0, vb0, tb0,
                                        sb1, vb1, tb1, W_pos, b_pos, h, hb);
    mfma_w1_final<<<M / 64, 256, 0, stream>>>(hb, wf + 7 * FRAG, b1,
                                              W2, b2, pos, out);
  }
}